// Round 1
// baseline (111.096 us; speedup 1.0000x reference)
//
#include <hip/hip_runtime.h>
#include <math.h>

#define NG    2048
#define IMG_W 128
#define IMG_H 128
#define TILE  16               // 16x16 px tiles, 8x8 = 64 tiles
#define MAXH  512              // hit cap per tile (mean ~70, 50-sigma margin)
#define F_FX  100.0f
#define F_FY  100.0f
#define NEARZ 1.1f
#define EPS_C 1e-6f
#define LIMU  (IMG_W / (2.0f * F_FX))
#define LIMV  (IMG_H / (2.0f * F_FY))
#define LOG2E 1.4426950408889634f
#define L2CUT 30.0f            // log2 alpha cutoff: culled pairs < opa*2^-30
#define TEXIT 1e-5f            // transmittance early-exit; residual error <= TEXIT

// Single dispatch, 64 blocks (one per tile), 256 threads (one per pixel).
// Each block redundantly preps all 2048 gaussians (projection+conic+bbox),
// compacts tile hits into LDS, rank-orders them by globally-consistent depth
// keys (exact reference permutation restricted to the hit set), and
// composites front-to-back with a saturation early-exit.
//
// R(this): phase-1 compaction is now BARRIER-FREE — per-wave ballot + one LDS
// atomicAdd by lane 0 (compaction order is irrelevant: phase 2 re-ranks by
// depth key). This deletes the 16 per-chunk __syncthreads that previously
// forced a vmcnt drain per chunk and serialized the 8 chunks' global-load
// latency; the fully-unrolled chunks now pipeline their loads.

__device__ __forceinline__ void quat_to_rot(float w, float x, float y, float z,
                                            float R[9]) {
    float n = sqrtf(w * w + x * x + y * y + z * z) + 1e-12f;
    w /= n; x /= n; y /= n; z /= n;
    R[0] = 1.0f - 2.0f * (y * y + z * z);
    R[1] = 2.0f * (x * y - w * z);
    R[2] = 2.0f * (x * z + w * y);
    R[3] = 2.0f * (x * y + w * z);
    R[4] = 1.0f - 2.0f * (x * x + z * z);
    R[5] = 2.0f * (y * z - w * x);
    R[6] = 2.0f * (x * z - w * y);
    R[7] = 2.0f * (y * z + w * x);
    R[8] = 1.0f - 2.0f * (x * x + y * y);
}

__global__ __launch_bounds__(256) void splat_fused_kernel(
    const float* __restrict__ pos, const float* __restrict__ rgb,
    const float* __restrict__ opa, const float* __restrict__ quat,
    const float* __restrict__ scale, const float* __restrict__ wq,
    const float* __restrict__ wt, float* __restrict__ out) {
    __shared__ __align__(16) float srec[MAXH * 12];         // 24 KB
    __shared__ __align__(16) unsigned long long skey[MAXH]; // 4 KB
    __shared__ unsigned short ord[MAXH];                    // 1 KB
    __shared__ int scnt;

    const int tid = threadIdx.x;
    const int lane = tid & 63;
    const int tx = blockIdx.x & 7;
    const int ty = blockIdx.x >> 3;

    // camera rotation (uniform, cheap)
    float cm[9];
    quat_to_rot(wq[0], wq[1], wq[2], wq[3], cm);
    const float t0 = wt[0], t1 = wt[1], t2 = wt[2];

    // tile bounds in camera-plane coords (pixel centers)
    const float ulo = (tx * TILE + 0.5f - IMG_W * 0.5f) / F_FX;
    const float uhi = (tx * TILE + TILE - 0.5f - IMG_W * 0.5f) / F_FX;
    const float vlo = (ty * TILE + 0.5f - IMG_H * 0.5f) / F_FY;
    const float vhi = (ty * TILE + TILE - 0.5f - IMG_H * 0.5f) / F_FY;

    if (tid == 0) scnt = 0;
    __syncthreads();

    // ---- phase 1: prep all gaussians, compact tile hits into LDS ----
    // No barriers inside the loop: hit slots are reserved via LDS atomicAdd
    // (order-free — phase 2 re-establishes exact depth order from the keys).
#pragma unroll
    for (int k = 0; k < NG / 256; ++k) {
        const int g = k * 256 + tid;
        const float px = pos[3 * g], py = pos[3 * g + 1], pz = pos[3 * g + 2];
        const float x = cm[0] * px + cm[1] * py + cm[2] * pz + t0;
        const float y = cm[3] * px + cm[4] * py + cm[5] * pz + t1;
        const float z = cm[6] * px + cm[7] * py + cm[8] * pz + t2;
        const float dn = sqrtf(x * x + y * y + z * z);
        bool m = z > NEARZ;
        const float zs = m ? z : 1.0f;
        const float u = x / zs;
        const float v = y / zs;
        m = m && (fabsf(u) < LIMU) && (fabsf(v) < LIMV);
        const float iz = 1.0f / zs;
        const float iz2 = iz * iz;

        const float4 q4 = *(const float4*)(quat + 4 * g);
        float Rg[9];
        quat_to_rot(q4.x, q4.y, q4.z, q4.w, Rg);
        const float s0 = scale[3 * g], s1 = scale[3 * g + 1],
                    s2 = scale[3 * g + 2];
        const float RS0 = Rg[0] * s0, RS1 = Rg[1] * s1, RS2 = Rg[2] * s2;
        const float RS3 = Rg[3] * s0, RS4 = Rg[4] * s1, RS5 = Rg[5] * s2;
        const float RS6 = Rg[6] * s0, RS7 = Rg[7] * s1, RS8 = Rg[8] * s2;

        const float xiz2 = x * iz2, yiz2 = y * iz2;
        const float w00 = iz * cm[0] - xiz2 * cm[6];
        const float w01 = iz * cm[1] - xiz2 * cm[7];
        const float w02 = iz * cm[2] - xiz2 * cm[8];
        const float w10 = iz * cm[3] - yiz2 * cm[6];
        const float w11 = iz * cm[4] - yiz2 * cm[7];
        const float w12 = iz * cm[5] - yiz2 * cm[8];

        const float e00 = w00 * RS0 + w01 * RS3 + w02 * RS6;
        const float e01 = w00 * RS1 + w01 * RS4 + w02 * RS7;
        const float e02 = w00 * RS2 + w01 * RS5 + w02 * RS8;
        const float e10 = w10 * RS0 + w11 * RS3 + w12 * RS6;
        const float e11 = w10 * RS1 + w11 * RS4 + w12 * RS7;
        const float e12 = w10 * RS2 + w11 * RS5 + w12 * RS8;

        const float a = e00 * e00 + e01 * e01 + e02 * e02 + EPS_C;
        const float b = e00 * e10 + e01 * e11 + e02 * e12;
        const float c = e10 * e10 + e11 * e11 + e12 * e12 + EPS_C;
        const float invdet = 1.0f / fmaxf(a * c - b * b, 1e-12f);
        // prescaled log2-domain conic: pw = A2*dx^2 + B2*dx*dy + C2*dy^2
        const float A2 = -0.5f * LOG2E * (c * invdet);
        const float C2 = -0.5f * LOG2E * (a * invdet);
        const float B2 = LOG2E * (b * invdet);

        // conservative bbox half-extents of the pw = -L2CUT level set
        bool hit = false;
        if (m) {
            const float dA = fminf(A2 - (B2 * B2) / (4.0f * C2), -1e-30f);
            const float dC = fminf(C2 - (B2 * B2) / (4.0f * A2), -1e-30f);
            const float dxm = sqrtf(-L2CUT / dA);
            const float dym = sqrtf(-L2CUT / dC);
            hit = (u + dxm >= ulo) && (u - dxm <= uhi) && (v + dym >= vlo) &&
                  (v - dym <= vhi);
        }

        const unsigned long long bal = __ballot(hit);
        const int nb = __popcll(bal);
        int wb = 0;
        if (lane == 0) wb = atomicAdd(&scnt, nb);
        wb = __shfl(wb, 0);
        const int off = wb + __popcll(bal & ((1ULL << lane) - 1ULL));
        if (hit && off < MAXH) {
            skey[off] = (((unsigned long long)__float_as_uint(dn)) << 32) |
                        (unsigned long long)(unsigned)g;
            float4* d = (float4*)(srec + off * 12);
            d[0] = make_float4(u, v, A2, B2);
            d[1] = make_float4(C2, opa[g], rgb[3 * g], rgb[3 * g + 1]);
            d[2] = make_float4(rgb[3 * g + 2], 0.0f, 0.0f, 0.0f);
        }
    }
    __syncthreads();
    const int cnt = min(scnt, MAXH);

    // ---- phase 2: rank-order hits (keys globally consistent & unique) ----
    for (int h = tid; h < cnt; h += 256) {
        const unsigned long long myk = skey[h];
        int rank = 0;
        for (int j = 0; j < cnt; ++j) rank += (skey[j] < myk) ? 1 : 0;
        ord[rank] = (unsigned short)h;
    }
    __syncthreads();

    // ---- phase 3: composite front-to-back, saturation early-exit ----
    const int lx = tid & (TILE - 1);
    const int ly = tid / TILE;
    const int ix = tx * TILE + lx;
    const int iy = ty * TILE + ly;
    const float pu = (ix + 0.5f - IMG_W * 0.5f) / F_FX;
    const float pv = (iy + 0.5f - IMG_H * 0.5f) / F_FY;

    float T = 1.0f, cr = 0.0f, cg = 0.0f, cb = 0.0f;
    for (int j = 0; j < cnt; ++j) {
        const int h = ord[j];
        const float4 q0 = ((const float4*)srec)[h * 3];      // u v A2 B2
        const float4 q1 = ((const float4*)srec)[h * 3 + 1];  // C2 o r g
        const float qb = srec[h * 12 + 8];                   // b
        const float dx = pu - q0.x;
        const float dy = pv - q0.y;
        const float pwa = fmaf(q0.z, dx, q0.w * dy);  // A2*dx + B2*dy
        float pw = fmaf(dx, pwa, q1.x * dy * dy);     // + C2*dy^2
        pw = fminf(pw, 0.0f);
        const float al = fminf(q1.y * __builtin_amdgcn_exp2f(pw), 0.99f);
        const float wgt = T * al;
        cr = fmaf(wgt, q1.z, cr);
        cg = fmaf(wgt, q1.w, cg);
        cb = fmaf(wgt, qb, cb);
        T -= wgt;  // == T*(1-al)
        // front-to-back in exact depth order: once every lane's T < TEXIT the
        // remaining contribution per channel is bounded by T (< 1e-5, far
        // below the 1e-3-scale pass threshold). Wave-uniform break.
        if (__all(T < TEXIT)) break;
    }

    const int p = iy * IMG_W + ix;
    out[3 * p + 0] = cr;
    out[3 * p + 1] = cg;
    out[3 * p + 2] = cb;
}

extern "C" void kernel_launch(void* const* d_in, const int* in_sizes, int n_in,
                              void* d_out, int out_size, void* d_ws,
                              size_t ws_size, hipStream_t stream) {
    const float* pos   = (const float*)d_in[0];
    const float* rgb   = (const float*)d_in[1];
    const float* opa   = (const float*)d_in[2];
    const float* quat  = (const float*)d_in[3];
    const float* scale = (const float*)d_in[4];
    const float* wq    = (const float*)d_in[5];
    const float* wt    = (const float*)d_in[6];
    float* out = (float*)d_out;

    splat_fused_kernel<<<64, 256, 0, stream>>>(pos, rgb, opa, quat, scale, wq,
                                               wt, out);
}

// Round 2
// 83.935 us; speedup vs baseline: 1.3236x; 1.3236x over previous
//
#include <hip/hip_runtime.h>
#include <math.h>

#define NG    2048
#define IMG_W 128
#define IMG_H 128
#define TILE  16               // 16x16 px tiles, 8x8 = 64 tiles
#define NTH   1024             // 16 waves/block: 4 waves/SIMD latency hiding
#define MAXH  512              // hit cap per tile (mean ~70, 50-sigma margin)
#define F_FX  100.0f
#define F_FY  100.0f
#define NEARZ 1.1f
#define EPS_C 1e-6f
#define LIMU  (IMG_W / (2.0f * F_FX))
#define LIMV  (IMG_H / (2.0f * F_FY))
#define LOG2E 1.4426950408889634f
#define L2CUT 30.0f            // log2 alpha cutoff: culled pairs < opa*2^-30

// Single dispatch, 64 blocks (one per tile), 1024 threads.
// Each block redundantly preps all 2048 gaussians (projection+conic+bbox),
// ballot-compacts tile hits into LDS via order-free atomic slot reservation
// (phase 2 re-establishes exact reference depth order from unique keys),
// rank-orders them, and composites front-to-back.
//
// R2 lessons baked in:
//  - NO per-iteration early-exit in phase 3 (R1: the __all(T)+break made the
//    loop latency-serialized, ~130cy/iter instead of pipelined ds_reads;
//    +20-30us on worst tiles). Inner loop is branch-free.
//  - 1024 threads (was 256): occupancy was 1.18% — latency-bound with no
//    hiding. Phase 1 now 2 chunks/thread; phase 3 splits each pixel's
//    composite over 4 depth segments (alpha compositing is associative:
//    C = Ca + Ta*Cb, T = Ta*Tb) with a final LDS combine.
//  - Barrier-free phase-1 compaction (per-wave ballot + one LDS atomicAdd).

__device__ __forceinline__ void quat_to_rot(float w, float x, float y, float z,
                                            float R[9]) {
    float n = sqrtf(w * w + x * x + y * y + z * z) + 1e-12f;
    w /= n; x /= n; y /= n; z /= n;
    R[0] = 1.0f - 2.0f * (y * y + z * z);
    R[1] = 2.0f * (x * y - w * z);
    R[2] = 2.0f * (x * z + w * y);
    R[3] = 2.0f * (x * y + w * z);
    R[4] = 1.0f - 2.0f * (x * x + z * z);
    R[5] = 2.0f * (y * z - w * x);
    R[6] = 2.0f * (x * z - w * y);
    R[7] = 2.0f * (y * z + w * x);
    R[8] = 1.0f - 2.0f * (x * x + y * y);
}

__global__ __launch_bounds__(NTH) void splat_fused_kernel(
    const float* __restrict__ pos, const float* __restrict__ rgb,
    const float* __restrict__ opa, const float* __restrict__ quat,
    const float* __restrict__ scale, const float* __restrict__ wq,
    const float* __restrict__ wt, float* __restrict__ out) {
    __shared__ __align__(16) float srec[MAXH * 12];         // 24 KB
    __shared__ __align__(16) unsigned long long skey[MAXH]; // 4 KB
    __shared__ __align__(16) float comb[NTH * 4];           // 16 KB
    __shared__ unsigned short ord[MAXH];                    // 1 KB
    __shared__ int scnt;

    const int tid = threadIdx.x;
    const int lane = tid & 63;
    const int tx = blockIdx.x & 7;
    const int ty = blockIdx.x >> 3;

    // camera rotation (uniform, cheap)
    float cm[9];
    quat_to_rot(wq[0], wq[1], wq[2], wq[3], cm);
    const float t0 = wt[0], t1 = wt[1], t2 = wt[2];

    // tile bounds in camera-plane coords (pixel centers)
    const float ulo = (tx * TILE + 0.5f - IMG_W * 0.5f) / F_FX;
    const float uhi = (tx * TILE + TILE - 0.5f - IMG_W * 0.5f) / F_FX;
    const float vlo = (ty * TILE + 0.5f - IMG_H * 0.5f) / F_FY;
    const float vhi = (ty * TILE + TILE - 0.5f - IMG_H * 0.5f) / F_FY;

    if (tid == 0) scnt = 0;
    __syncthreads();

    // ---- phase 1: prep all gaussians, compact tile hits into LDS ----
    // No barriers inside the loop: hit slots are reserved via LDS atomicAdd
    // (order-free — phase 2 re-establishes exact depth order from the keys).
#pragma unroll
    for (int k = 0; k < NG / NTH; ++k) {
        const int g = k * NTH + tid;
        const float px = pos[3 * g], py = pos[3 * g + 1], pz = pos[3 * g + 2];
        const float x = cm[0] * px + cm[1] * py + cm[2] * pz + t0;
        const float y = cm[3] * px + cm[4] * py + cm[5] * pz + t1;
        const float z = cm[6] * px + cm[7] * py + cm[8] * pz + t2;
        const float dn = sqrtf(x * x + y * y + z * z);
        bool m = z > NEARZ;
        const float zs = m ? z : 1.0f;
        const float u = x / zs;
        const float v = y / zs;
        m = m && (fabsf(u) < LIMU) && (fabsf(v) < LIMV);
        const float iz = 1.0f / zs;
        const float iz2 = iz * iz;

        const float4 q4 = *(const float4*)(quat + 4 * g);
        float Rg[9];
        quat_to_rot(q4.x, q4.y, q4.z, q4.w, Rg);
        const float s0 = scale[3 * g], s1 = scale[3 * g + 1],
                    s2 = scale[3 * g + 2];
        const float RS0 = Rg[0] * s0, RS1 = Rg[1] * s1, RS2 = Rg[2] * s2;
        const float RS3 = Rg[3] * s0, RS4 = Rg[4] * s1, RS5 = Rg[5] * s2;
        const float RS6 = Rg[6] * s0, RS7 = Rg[7] * s1, RS8 = Rg[8] * s2;

        const float xiz2 = x * iz2, yiz2 = y * iz2;
        const float w00 = iz * cm[0] - xiz2 * cm[6];
        const float w01 = iz * cm[1] - xiz2 * cm[7];
        const float w02 = iz * cm[2] - xiz2 * cm[8];
        const float w10 = iz * cm[3] - yiz2 * cm[6];
        const float w11 = iz * cm[4] - yiz2 * cm[7];
        const float w12 = iz * cm[5] - yiz2 * cm[8];

        const float e00 = w00 * RS0 + w01 * RS3 + w02 * RS6;
        const float e01 = w00 * RS1 + w01 * RS4 + w02 * RS7;
        const float e02 = w00 * RS2 + w01 * RS5 + w02 * RS8;
        const float e10 = w10 * RS0 + w11 * RS3 + w12 * RS6;
        const float e11 = w10 * RS1 + w11 * RS4 + w12 * RS7;
        const float e12 = w10 * RS2 + w11 * RS5 + w12 * RS8;

        const float a = e00 * e00 + e01 * e01 + e02 * e02 + EPS_C;
        const float b = e00 * e10 + e01 * e11 + e02 * e12;
        const float c = e10 * e10 + e11 * e11 + e12 * e12 + EPS_C;
        const float invdet = 1.0f / fmaxf(a * c - b * b, 1e-12f);
        // prescaled log2-domain conic: pw = A2*dx^2 + B2*dx*dy + C2*dy^2
        const float A2 = -0.5f * LOG2E * (c * invdet);
        const float C2 = -0.5f * LOG2E * (a * invdet);
        const float B2 = LOG2E * (b * invdet);

        // conservative bbox half-extents of the pw = -L2CUT level set
        bool hit = false;
        if (m) {
            const float dA = fminf(A2 - (B2 * B2) / (4.0f * C2), -1e-30f);
            const float dC = fminf(C2 - (B2 * B2) / (4.0f * A2), -1e-30f);
            const float dxm = sqrtf(-L2CUT / dA);
            const float dym = sqrtf(-L2CUT / dC);
            hit = (u + dxm >= ulo) && (u - dxm <= uhi) && (v + dym >= vlo) &&
                  (v - dym <= vhi);
        }

        const unsigned long long bal = __ballot(hit);
        const int nb = __popcll(bal);
        int wb = 0;
        if (lane == 0) wb = atomicAdd(&scnt, nb);
        wb = __shfl(wb, 0);
        const int off = wb + __popcll(bal & ((1ULL << lane) - 1ULL));
        if (hit && off < MAXH) {
            skey[off] = (((unsigned long long)__float_as_uint(dn)) << 32) |
                        (unsigned long long)(unsigned)g;
            float4* d = (float4*)(srec + off * 12);
            d[0] = make_float4(u, v, A2, B2);
            d[1] = make_float4(C2, opa[g], rgb[3 * g], rgb[3 * g + 1]);
            d[2] = make_float4(rgb[3 * g + 2], 0.0f, 0.0f, 0.0f);
        }
    }
    __syncthreads();
    const int cnt = min(scnt, MAXH);

    // ---- phase 2: rank-order hits (keys globally consistent & unique) ----
    for (int h = tid; h < cnt; h += NTH) {
        const unsigned long long myk = skey[h];
        int rank = 0;
        for (int j = 0; j < cnt; ++j) rank += (skey[j] < myk) ? 1 : 0;
        ord[rank] = (unsigned short)h;
    }
    __syncthreads();

    // ---- phase 3: composite front-to-back, 4 depth segments per pixel ----
    // Alpha compositing is associative over segments: (C,T) combine as
    // C = Ca + Ta*Cb, T = Ta*Tb. Threads {pix, pix+256, pix+512, pix+768}
    // handle disjoint depth quarters of pixel pix; LDS combine at the end.
    const int seg = tid >> 8;   // 0..3 (0 = nearest)
    const int pix = tid & 255;
    const int lx = pix & (TILE - 1);
    const int ly = pix >> 4;
    const int ix = tx * TILE + lx;
    const int iy = ty * TILE + ly;
    const float pu = (ix + 0.5f - IMG_W * 0.5f) / F_FX;
    const float pv = (iy + 0.5f - IMG_H * 0.5f) / F_FY;

    const int cnt4 = (cnt + 3) >> 2;
    const int j0 = seg * cnt4;
    const int j1 = min(j0 + cnt4, cnt);

    float T = 1.0f, cr = 0.0f, cg = 0.0f, cb = 0.0f;
    for (int j = j0; j < j1; ++j) {   // branch-free body: pipelined ds_reads
        const int h = ord[j];
        const float4 q0 = ((const float4*)srec)[h * 3];      // u v A2 B2
        const float4 q1 = ((const float4*)srec)[h * 3 + 1];  // C2 o r g
        const float qb = srec[h * 12 + 8];                   // b
        const float dx = pu - q0.x;
        const float dy = pv - q0.y;
        const float pwa = fmaf(q0.z, dx, q0.w * dy);  // A2*dx + B2*dy
        float pw = fmaf(dx, pwa, q1.x * dy * dy);     // + C2*dy^2
        pw = fminf(pw, 0.0f);
        const float al = fminf(q1.y * __builtin_amdgcn_exp2f(pw), 0.99f);
        const float wgt = T * al;
        cr = fmaf(wgt, q1.z, cr);
        cg = fmaf(wgt, q1.w, cg);
        cb = fmaf(wgt, qb, cb);
        T -= wgt;  // == T*(1-al)
    }

    ((float4*)comb)[tid] = make_float4(cr, cg, cb, T);  // stride-16B: no conflicts
    __syncthreads();

    if (tid < 256) {  // pix == tid here
        const float4 s0 = ((const float4*)comb)[pix];
        const float4 s1 = ((const float4*)comb)[256 + pix];
        const float4 s2 = ((const float4*)comb)[512 + pix];
        const float4 s3 = ((const float4*)comb)[768 + pix];
        // front-to-back segment combine
        const float R = s0.x + s0.w * (s1.x + s1.w * (s2.x + s2.w * s3.x));
        const float G = s0.y + s0.w * (s1.y + s1.w * (s2.y + s2.w * s3.y));
        const float B = s0.z + s0.w * (s1.z + s1.w * (s2.z + s2.w * s3.z));
        const int p = iy * IMG_W + ix;
        out[3 * p + 0] = R;
        out[3 * p + 1] = G;
        out[3 * p + 2] = B;
    }
}

extern "C" void kernel_launch(void* const* d_in, const int* in_sizes, int n_in,
                              void* d_out, int out_size, void* d_ws,
                              size_t ws_size, hipStream_t stream) {
    const float* pos   = (const float*)d_in[0];
    const float* rgb   = (const float*)d_in[1];
    const float* opa   = (const float*)d_in[2];
    const float* quat  = (const float*)d_in[3];
    const float* scale = (const float*)d_in[4];
    const float* wq    = (const float*)d_in[5];
    const float* wt    = (const float*)d_in[6];
    float* out = (float*)d_out;

    splat_fused_kernel<<<64, NTH, 0, stream>>>(pos, rgb, opa, quat, scale, wq,
                                               wt, out);
}